// Round 4
// baseline (106.443 us; speedup 1.0000x reference)
//
#include <hip/hip_runtime.h>
#include <math.h>

#define NCLS 80
#define DEPS 1e-7f

__global__ void yolo_zero(float* out) { out[0] = 0.0f; }

// One wave (64 threads) per (scale, batch, target).
__global__ void yolo_loss_kernel(const float* __restrict__ p0,
                                 const float* __restrict__ p1,
                                 const float* __restrict__ p2,
                                 const float* __restrict__ boxes,
                                 const int* __restrict__ labels,
                                 float* __restrict__ out) {
    const int bid = blockIdx.x;          // 0..767
    const int s   = bid >> 8;            // scale 0..2
    const int rem = bid & 255;
    const int b   = rem >> 5;            // batch 0..7
    const int t   = rem & 31;            // target 0..31
    const int lane = threadIdx.x;        // 0..63

    // per-scale constants
    const int   nx     = (s == 0) ? 80 : (s == 1) ? 40 : 20;
    const float stride = (s == 0) ? 8.0f : (s == 1) ? 16.0f : 32.0f;
    const float* p     = (s == 0) ? p0 : (s == 1) ? p1 : p2;

    // anchors [scale][k]
    const float AW[3][3] = {{10.f, 16.f, 33.f}, {30.f, 62.f, 59.f}, {116.f, 156.f, 373.f}};
    const float AH[3][3] = {{13.f, 30.f, 23.f}, {61.f, 45.f, 119.f}, {90.f, 198.f, 326.f}};

    // target box (all coords scaled by nx, faithful to reference)
    const float* bx = boxes + (size_t)(b * 32 + t) * 4;
    const float gxc = bx[0] * (float)nx;
    const float gyc = bx[1] * (float)nx;
    const float gw  = bx[2] * (float)nx;
    const float gh  = bx[3] * (float)nx;

    int gi = (int)floorf(gxc); gi = min(max(gi, 0), nx - 1);
    int gj = (int)floorf(gyc); gj = min(max(gj, 0), nx - 1);

    // anchor assignment: argmin over k of max(max(r, 1/r)) — first-min tiebreak
    int a = 0;
    float best = 3.402823e38f;
    #pragma unroll
    for (int k = 0; k < 3; ++k) {
        const float aw = AW[s][k] / stride;
        const float ah = AH[s][k] / stride;
        float rx = gw / aw; rx = fmaxf(rx, 1.0f / rx);
        float ry = gh / ah; ry = fmaxf(ry, 1.0f / ry);
        const float m = fmaxf(rx, ry);
        if (m < best) { best = m; a = k; }
    }

    const int lab = labels[b * 32 + t];

    // gather channels: element [b, a*85+c, gj, gi], plane = nx*nx
    const long long plane = (long long)nx * (long long)nx;
    const float* base = p + ((long long)b * 255 + (long long)a * 85) * plane
                          + (long long)gj * nx + gi;

    const float v0 = base[(long long)lane * plane];                 // channel = lane (0..63)
    const float v1 = (lane < 21) ? base[(long long)(lane + 64) * plane] : 0.0f; // 64..84

    // class BCE partials (channels 5..84 -> classes 0..79)
    // pred_cls = sigmoid(logit); bce(x,y) with x>0: x - x*y + log1p(exp(-x))
    float cls = 0.0f;
    if (lane >= 5) {
        const int c = lane - 5;
        const float x = 1.0f / (1.0f + expf(-v0));
        const float y = (c == lab) ? 1.0f : 0.0f;
        cls += x - x * y + log1pf(expf(-x));
    }
    if (lane < 21) {
        const int c = lane + 59;
        const float x = 1.0f / (1.0f + expf(-v1));
        const float y = (c == lab) ? 1.0f : 0.0f;
        cls += x - x * y + log1pf(expf(-x));
    }

    // wave reduction of cls into lane 0
    #pragma unroll
    for (int off = 32; off > 0; off >>= 1)
        cls += __shfl_down(cls, off, 64);

    // broadcast box/obj channels (lanes 0..4 hold them in v0)
    const float pxl = __shfl(v0, 0, 64);
    const float pyl = __shfl(v0, 1, 64);
    const float pwl = __shfl(v0, 2, 64);
    const float phl = __shfl(v0, 3, 64);
    const float pol = __shfl(v0, 4, 64);

    if (lane == 0) {
        // predicted box (faithful: + grid offset), target box (cell-relative)
        const float sx = 1.0f / (1.0f + expf(-pxl));
        const float sy = 1.0f / (1.0f + expf(-pyl));
        const float aw = AW[s][a] / stride;
        const float ah = AH[s][a] / stride;
        const float pw = expf(pwl) * aw;
        const float ph = expf(phl) * ah;

        const float b1cx = sx + (float)gi;
        const float b1cy = sy + (float)gj;
        const float b2cx = gxc - (float)gi;
        const float b2cy = gyc - (float)gj;

        // diou_xywh(b1, b2) — EPS placement exactly as reference
        const float b1x1 = b1cx - pw * 0.5f, b1x2 = b1cx + pw * 0.5f;
        const float b1y1 = b1cy - ph * 0.5f, b1y2 = b1cy + ph * 0.5f;
        const float b2x1 = b2cx - gw * 0.5f, b2x2 = b2cx + gw * 0.5f;
        const float b2y1 = b2cy - gh * 0.5f, b2y2 = b2cy + gh * 0.5f;

        const float iw = fmaxf(fminf(b1x2, b2x2) - fmaxf(b1x1, b2x1), 0.0f);
        const float ih = fmaxf(fminf(b1y2, b2y2) - fmaxf(b1y1, b2y1), 0.0f);
        const float inter = iw * ih;

        const float w1 = b1x2 - b1x1, h1 = b1y2 - b1y1 + DEPS;
        const float w2 = b2x2 - b2x1, h2 = b2y2 - b2y1 + DEPS;
        const float uni = w1 * h1 + w2 * h2 - inter + DEPS;
        const float iou = inter / uni;

        const float cw = fmaxf(b1x2, b2x2) - fminf(b1x1, b2x1);
        const float ch = fmaxf(b1y2, b2y2) - fminf(b1y1, b2y1);
        const float c2 = cw * cw + ch * ch + DEPS;
        const float dx = b2x1 + b2x2 - b1x1 - b1x2;
        const float dy = b2y1 + b2y2 - b1y1 - b1y2;
        const float rho2 = (dx * dx + dy * dy) * 0.25f;
        const float diou = iou - rho2 / c2;

        // obj: BCE applied to sigmoided value (faithful quirk), target 1
        const float so   = 1.0f / (1.0f + expf(-pol));
        const float lobj = log1pf(expf(-so));

        const float total = 5.0f * (1.0f - diou) + lobj + cls * (1.0f / (float)NCLS);
        atomicAdd(out, total);
    }
}

extern "C" void kernel_launch(void* const* d_in, const int* in_sizes, int n_in,
                              void* d_out, int out_size, void* d_ws, size_t ws_size,
                              hipStream_t stream) {
    const float* p0    = (const float*)d_in[0];
    const float* p1    = (const float*)d_in[1];
    const float* p2    = (const float*)d_in[2];
    const float* boxes = (const float*)d_in[3];
    const int*   labels = (const int*)d_in[4];
    float* out = (float*)d_out;

    yolo_zero<<<1, 1, 0, stream>>>(out);
    yolo_loss_kernel<<<768, 64, 0, stream>>>(p0, p1, p2, boxes, labels, out);
}

// Round 7
// 106.043 us; speedup vs baseline: 1.0038x; 1.0038x over previous
//
#include <hip/hip_runtime.h>
#include <math.h>

#define NCLS 80
#define DEPS 1e-7f

// One wave (64 threads) per (scale, batch, target).
__global__ void yolo_loss_kernel(const float* __restrict__ p0,
                                 const float* __restrict__ p1,
                                 const float* __restrict__ p2,
                                 const float* __restrict__ boxes,
                                 const int* __restrict__ labels,
                                 float* __restrict__ out) {
    const int bid = blockIdx.x;          // 0..767
    const int s   = bid >> 8;            // scale 0..2
    const int rem = bid & 255;
    const int b   = rem >> 5;            // batch 0..7
    const int t   = rem & 31;            // target 0..31
    const int lane = threadIdx.x;        // 0..63

    // per-scale constants
    const int   nx     = (s == 0) ? 80 : (s == 1) ? 40 : 20;
    const float stride = (s == 0) ? 8.0f : (s == 1) ? 16.0f : 32.0f;
    const float* p     = (s == 0) ? p0 : (s == 1) ? p1 : p2;

    // anchors [scale][k]
    const float AW[3][3] = {{10.f, 16.f, 33.f}, {30.f, 62.f, 59.f}, {116.f, 156.f, 373.f}};
    const float AH[3][3] = {{13.f, 30.f, 23.f}, {61.f, 45.f, 119.f}, {90.f, 198.f, 326.f}};

    // target box (all coords scaled by nx, faithful to reference)
    const float* bx = boxes + (size_t)(b * 32 + t) * 4;
    const float gxc = bx[0] * (float)nx;
    const float gyc = bx[1] * (float)nx;
    const float gw  = bx[2] * (float)nx;
    const float gh  = bx[3] * (float)nx;

    int gi = (int)floorf(gxc); gi = min(max(gi, 0), nx - 1);
    int gj = (int)floorf(gyc); gj = min(max(gj, 0), nx - 1);

    // anchor assignment: argmin over k of max(max(r, 1/r)) — first-min tiebreak
    int a = 0;
    float best = 3.402823e38f;
    #pragma unroll
    for (int k = 0; k < 3; ++k) {
        const float aw = AW[s][k] / stride;
        const float ah = AH[s][k] / stride;
        float rx = gw / aw; rx = fmaxf(rx, 1.0f / rx);
        float ry = gh / ah; ry = fmaxf(ry, 1.0f / ry);
        const float m = fmaxf(rx, ry);
        if (m < best) { best = m; a = k; }
    }

    const int lab = labels[b * 32 + t];

    // gather channels: element [b, a*85+c, gj, gi], plane = nx*nx
    const long long plane = (long long)nx * (long long)nx;
    const float* base = p + ((long long)b * 255 + (long long)a * 85) * plane
                          + (long long)gj * nx + gi;

    const float v0 = base[(long long)lane * plane];                 // channel = lane (0..63)
    const float v1 = (lane < 21) ? base[(long long)(lane + 64) * plane] : 0.0f; // 64..84

    // class BCE partials (channels 5..84 -> classes 0..79)
    // pred_cls = sigmoid(logit); bce(x,y): x - x*y + log1p(exp(-x)) for x>0
    float cls = 0.0f;
    if (lane >= 5) {
        const int c = lane - 5;
        const float x = 1.0f / (1.0f + expf(-v0));
        const float y = (c == lab) ? 1.0f : 0.0f;
        cls += x - x * y + log1pf(expf(-x));
    }
    if (lane < 21) {
        const int c = lane + 59;
        const float x = 1.0f / (1.0f + expf(-v1));
        const float y = (c == lab) ? 1.0f : 0.0f;
        cls += x - x * y + log1pf(expf(-x));
    }

    // wave reduction of cls into lane 0
    #pragma unroll
    for (int off = 32; off > 0; off >>= 1)
        cls += __shfl_down(cls, off, 64);

    // broadcast box/obj channels (lanes 0..4 hold them in v0)
    const float pxl = __shfl(v0, 0, 64);
    const float pyl = __shfl(v0, 1, 64);
    const float pwl = __shfl(v0, 2, 64);
    const float phl = __shfl(v0, 3, 64);
    const float pol = __shfl(v0, 4, 64);

    if (lane == 0) {
        // predicted box (faithful: + grid offset), target box (cell-relative)
        const float sx = 1.0f / (1.0f + expf(-pxl));
        const float sy = 1.0f / (1.0f + expf(-pyl));
        const float aw = AW[s][a] / stride;
        const float ah = AH[s][a] / stride;
        const float pw = expf(pwl) * aw;
        const float ph = expf(phl) * ah;

        const float b1cx = sx + (float)gi;
        const float b1cy = sy + (float)gj;
        const float b2cx = gxc - (float)gi;
        const float b2cy = gyc - (float)gj;

        // diou_xywh(b1, b2) — EPS placement exactly as reference
        const float b1x1 = b1cx - pw * 0.5f, b1x2 = b1cx + pw * 0.5f;
        const float b1y1 = b1cy - ph * 0.5f, b1y2 = b1cy + ph * 0.5f;
        const float b2x1 = b2cx - gw * 0.5f, b2x2 = b2cx + gw * 0.5f;
        const float b2y1 = b2cy - gh * 0.5f, b2y2 = b2cy + gh * 0.5f;

        const float iw = fmaxf(fminf(b1x2, b2x2) - fmaxf(b1x1, b2x1), 0.0f);
        const float ih = fmaxf(fminf(b1y2, b2y2) - fmaxf(b1y1, b2y1), 0.0f);
        const float inter = iw * ih;

        const float w1 = b1x2 - b1x1, h1 = b1y2 - b1y1 + DEPS;
        const float w2 = b2x2 - b2x1, h2 = b2y2 - b2y1 + DEPS;
        const float uni = w1 * h1 + w2 * h2 - inter + DEPS;
        const float iou = inter / uni;

        const float cw = fmaxf(b1x2, b2x2) - fminf(b1x1, b2x1);
        const float ch = fmaxf(b1y2, b2y2) - fminf(b1y1, b2y1);
        const float c2 = cw * cw + ch * ch + DEPS;
        const float dx = b2x1 + b2x2 - b1x1 - b1x2;
        const float dy = b2y1 + b2y2 - b1y1 - b1y2;
        const float rho2 = (dx * dx + dy * dy) * 0.25f;
        const float diou = iou - rho2 / c2;

        // obj: BCE applied to sigmoided value (faithful quirk), target 1
        const float so   = 1.0f / (1.0f + expf(-pol));
        const float lobj = log1pf(expf(-so));

        const float total = 5.0f * (1.0f - diou) + lobj + cls * (1.0f / (float)NCLS);
        atomicAdd(out, total);
    }
}

extern "C" void kernel_launch(void* const* d_in, const int* in_sizes, int n_in,
                              void* d_out, int out_size, void* d_ws, size_t ws_size,
                              hipStream_t stream) {
    const float* p0    = (const float*)d_in[0];
    const float* p1    = (const float*)d_in[1];
    const float* p2    = (const float*)d_in[2];
    const float* boxes = (const float*)d_in[3];
    const int*   labels = (const int*)d_in[4];
    float* out = (float*)d_out;

    // Zero the (0xAA-poisoned) scalar output with a graph-capturable DMA
    // memset node instead of a 1-thread kernel launch.
    hipMemsetAsync(out, 0, sizeof(float) * (size_t)out_size, stream);
    yolo_loss_kernel<<<768, 64, 0, stream>>>(p0, p1, p2, boxes, labels, out);
}